// Round 3
// baseline (294.057 us; speedup 1.0000x reference)
//
#include <hip/hip_runtime.h>
#include <stdint.h>

#define NB 131072     // batch
#define MS 64         // samples per block
#define ROWS 264      // shorts per LDS activation row (528 B, 16B-aligned, +4 pad)

typedef __bf16 bf16x8 __attribute__((ext_vector_type(8)));
typedef short  s16x8  __attribute__((ext_vector_type(8)));
typedef float  f32x4  __attribute__((ext_vector_type(4)));
typedef float  f32x2  __attribute__((ext_vector_type(2)));

static __device__ __forceinline__ short f2bf(float f){
  uint32_t u = __builtin_bit_cast(uint32_t, f);
  u = (u + 0x7fffu + ((u >> 16) & 1u)) >> 16;   // RNE
  return (short)(uint16_t)u;
}
static __device__ __forceinline__ float bf2f(short s){
  uint32_t u = ((uint32_t)(uint16_t)s) << 16;
  return __builtin_bit_cast(float, u);
}
static __device__ __forceinline__ float fast_tanh(float x){
  // tanh(x) = 1 - 2/(e^{2x}+1); v_exp + v_rcp, ~1e-6 abs err, saturates correctly
  float e = __expf(2.0f * x);
  return 1.0f - 2.0f * __builtin_amdgcn_rcpf(e + 1.0f);
}
static __device__ __forceinline__ float rsum16(float v){
  v += __shfl_xor(v, 1);
  v += __shfl_xor(v, 2);
  v += __shfl_xor(v, 4);
  v += __shfl_xor(v, 8);
  return v;
}

// ---- GEMM core: 64x256 out tile, K=256. A from LDS (bf16), B from global bf16 (L2-hot).
// Wave w computes cols [64w, 64w+64). Layouts (m89/m92-verified):
//   A row=l&15, k=(l>>4)*8+e;  B col=l&15, k=(l>>4)*8+e;  D col=l&15, row=(l>>4)*4+r.
static __device__ __forceinline__ void gemm_core(
    const short* bufA_, const short* __restrict__ Wb,
    int w, int lm, int q, f32x4 acc[4][4])
{
#pragma unroll
  for (int mi=0;mi<4;mi++)
#pragma unroll
    for (int nj=0;nj<4;nj++)
      acc[mi][nj] = (f32x4){0.f,0.f,0.f,0.f};
  const short* ap = bufA_ + lm*ROWS + q*8;
  const short* bp = Wb + (64*w + lm)*256 + q*8;
#pragma unroll
  for (int ks=0; ks<8; ++ks){
    bf16x8 af[4], bfr[4];
#pragma unroll
    for (int mi=0;mi<4;mi++)
      af[mi] = *(const bf16x8*)(ap + 16*mi*ROWS + 32*ks);
#pragma unroll
    for (int nj=0;nj<4;nj++)
      bfr[nj] = *(const bf16x8*)(bp + 16*nj*256 + 32*ks);
#pragma unroll
    for (int mi=0;mi<4;mi++)
#pragma unroll
      for (int nj=0;nj<4;nj++)
        acc[mi][nj] = __builtin_amdgcn_mfma_f32_16x16x32_bf16(af[mi], bfr[nj], acc[mi][nj], 0, 0, 0);
  }
}

// ---- stage: act1 = tanh(x*W1^T + b1) -> bf16 LDS tile [64][256] (stride ROWS)
static __device__ __forceinline__ void stage_act(
    int tid, const float* __restrict__ W1, const float* __restrict__ b1,
    float x0, float x1, short* buf)
{
  const int s  = tid & 63;
  const int wq = tid >> 6;
#pragma unroll
  for (int it=0; it<8; ++it){
    const int k0 = (wq + 4*it) * 8;
    // wave-uniform weight loads -> scalar loads
    f32x4 wa = *(const f32x4*)(W1 + k0*2);
    f32x4 wb = *(const f32x4*)(W1 + k0*2 + 4);
    f32x4 wc = *(const f32x4*)(W1 + k0*2 + 8);
    f32x4 wd = *(const f32x4*)(W1 + k0*2 + 12);
    f32x4 ba = *(const f32x4*)(b1 + k0);
    f32x4 bb = *(const f32x4*)(b1 + k0 + 4);
    s16x8 p;
    p[0] = f2bf(fast_tanh(x0*wa.x + x1*wa.y + ba.x));
    p[1] = f2bf(fast_tanh(x0*wa.z + x1*wa.w + ba.y));
    p[2] = f2bf(fast_tanh(x0*wb.x + x1*wb.y + ba.z));
    p[3] = f2bf(fast_tanh(x0*wb.z + x1*wb.w + ba.w));
    p[4] = f2bf(fast_tanh(x0*wc.x + x1*wc.y + bb.x));
    p[5] = f2bf(fast_tanh(x0*wc.z + x1*wc.w + bb.y));
    p[6] = f2bf(fast_tanh(x0*wd.x + x1*wd.y + bb.z));
    p[7] = f2bf(fast_tanh(x0*wd.z + x1*wd.w + bb.w));
    *(s16x8*)(buf + s*ROWS + k0) = p;
  }
}

// ---- fwd epilogue: act2 = tanh(acc+b2); write derivative-weighted "a"/"c" to bufB (GEMM2 A-operand);
// row-reduce (V: sum act2^2, H: sum W3*act2) into rs[w][srow].
template<int ISH>
static __device__ __forceinline__ void epi_fwd(
    f32x4 acc[4][4], const float* __restrict__ b2, const float* __restrict__ W3,
    short* bufB_, int w, int lm, int q, float* __restrict__ rs)
{
  float b2v[4], w3v[4];
#pragma unroll
  for (int nj=0;nj<4;nj++){
    const int h = 64*w + 16*nj + lm;
    b2v[nj] = b2[h];
    w3v[nj] = ISH ? W3[h] : 0.f;
  }
#pragma unroll
  for (int mi=0;mi<4;mi++){
#pragma unroll
    for (int r=0;r<4;r++){
      const int srow = 16*mi + 4*q + r;
      float part = 0.f;
#pragma unroll
      for (int nj=0;nj<4;nj++){
        const int h = 64*w + 16*nj + lm;
        const float t = fast_tanh(acc[mi][nj][r] + b2v[nj]);
        float d;
        if (ISH){ part += w3v[nj]*t; d = w3v[nj]*(1.f - t*t); }
        else    { part += t*t;       d = t*(1.f - t*t); }
        bufB_[srow*ROWS + h] = f2bf(d);
      }
      const float tot = rsum16(part);
      if (lm == 0) rs[w*MS + srow] = tot;
    }
  }
}

// ---- bwd epilogue: acc = t[s][kc]; grad_n = sum_kc t*(1-act1^2)*W1[kc][n] -> g0s/g1s[w][srow]
static __device__ __forceinline__ void epi_bwd(
    f32x4 acc[4][4], const short* bufA_, const float* __restrict__ W1,
    int w, int lm, int q, float* __restrict__ g0s, float* __restrict__ g1s)
{
  f32x2 w1v[4];
  int kc[4];
#pragma unroll
  for (int nj=0;nj<4;nj++){
    kc[nj] = 64*w + 16*nj + lm;
    w1v[nj] = *(const f32x2*)(W1 + 2*kc[nj]);
  }
#pragma unroll
  for (int mi=0;mi<4;mi++){
#pragma unroll
    for (int r=0;r<4;r++){
      const int srow = 16*mi + 4*q + r;
      float g0 = 0.f, g1 = 0.f;
#pragma unroll
      for (int nj=0;nj<4;nj++){
        const float v1 = bf2f(bufA_[srow*ROWS + kc[nj]]);
        const float fac = acc[mi][nj][r] * (1.f - v1*v1);
        g0 += fac * w1v[nj].x;
        g1 += fac * w1v[nj].y;
      }
      const float t0 = rsum16(g0);
      const float t1 = rsum16(g1);
      if (lm == 0){ g0s[w*MS + srow] = t0; g1s[w*MS + srow] = t1; }
    }
  }
}

__global__ __launch_bounds__(256, 2)
void fused(const float* __restrict__ x,
           const float* __restrict__ VW1, const float* __restrict__ Vb1, const float* __restrict__ Vb2,
           const float* __restrict__ HW1, const float* __restrict__ Hb1, const float* __restrict__ Hb2,
           const float* __restrict__ HW3, const float* __restrict__ Hb3,
           const float* __restrict__ uW1, const float* __restrict__ ub1,
           const float* __restrict__ uW2, const float* __restrict__ ub2,
           const short* __restrict__ VW2bf, const short* __restrict__ VW2T,
           const short* __restrict__ HW2bf, const short* __restrict__ HW2T,
           float* __restrict__ out)
{
  __shared__ __attribute__((aligned(16))) short bufA[MS*ROWS];
  __shared__ __attribute__((aligned(16))) short bufB[MS*ROWS];
  __shared__ float xs[MS][2];
  __shared__ float redu[7][4][MS];  // Vsum, gv0, gv1, Hsum, gh0raw, gh1raw, upart

  const int tid = (int)threadIdx.x;
  const int w = tid >> 6, l = tid & 63, lm = l & 15, q = l >> 4;
  const int s0 = (int)blockIdx.x * MS;

  if (tid < 128) ((float*)xs)[tid] = x[s0*2 + tid];
  __syncthreads();

  const float x0 = xs[tid & 63][0], x1 = xs[tid & 63][1];

  f32x4 acc[4][4];

  // ================= V path =================
  stage_act(tid, VW1, Vb1, x0, x1, bufA);
  __syncthreads();
  gemm_core(bufA, VW2bf, w, lm, q, acc);
  epi_fwd<0>(acc, Vb2, (const float*)nullptr, bufB, w, lm, q, &redu[0][0][0]);
  __syncthreads();
  gemm_core(bufB, VW2T, w, lm, q, acc);
  epi_bwd(acc, bufA, VW1, w, lm, q, &redu[1][0][0], &redu[2][0][0]);
  __syncthreads();

  // ================= H path =================
  stage_act(tid, HW1, Hb1, x0, x1, bufA);
  __syncthreads();
  gemm_core(bufA, HW2bf, w, lm, q, acc);
  epi_fwd<1>(acc, Hb2, HW3, bufB, w, lm, q, &redu[3][0][0]);
  __syncthreads();
  gemm_core(bufB, HW2T, w, lm, q, acc);
  epi_bwd(acc, bufA, HW1, w, lm, q, &redu[4][0][0], &redu[5][0][0]);

  // ================= u path ================= (wave-uniform weight rows -> s_loads)
  {
    float up = 0.f;
    const int h0 = 64 * w;
#pragma unroll 8
    for (int i=0;i<64;i++){
      const int h = h0 + i;
      up += uW2[h] * fast_tanh(x0*uW1[2*h] + x1*uW1[2*h+1] + ub1[h]);
    }
    redu[6][w][tid & 63] = up;
  }
  __syncthreads();

  // ================= final combine =================
  if (tid < MS){
    const int s = tid;
    float sv=0.f, a0=0.f, a1=0.f, hp=0.f, b0=0.f, b1v=0.f, us=0.f;
#pragma unroll
    for (int j=0;j<4;j++){
      sv += redu[0][j][s]; a0 += redu[1][j][s]; a1 += redu[2][j][s];
      hp += redu[3][j][s]; b0 += redu[4][j][s]; b1v+= redu[5][j][s];
      us += redu[6][j][s];
    }
    const float V  = 0.5f * sv;
    const float u  = fast_tanh(us + ub2[0]);
    const float H  = fast_tanh(hp + Hb3[0]);
    const float dH = 1.f - H*H;
    const float gh0 = dH*b0, gh1 = dH*b1v;
    const float xx0 = xs[s][0], xx1 = xs[s][1];
    const float f0 = xx1;
    const float f1 = -sinf(xx0) - 0.1f*xx1;
    const float Vdot = a0*f0 + a1*f1 + a1*u;   // L_f_V + grad_V[1]*u
    const float Hdot = gh0*f0 + gh1*f1 + gh1*u;
    const int gs = s0 + s;
    out[gs]        = u;
    out[NB + gs]   = V;
    out[2*NB + gs] = Vdot;
    out[3*NB + gs] = H;
    out[4*NB + gs] = Hdot;
  }
}

// ---- pre-kernel: fp32 weights -> bf16 row-major + bf16 transposed copies in d_ws
__global__ __launch_bounds__(256)
void cvt_w(const float* __restrict__ VW2, const float* __restrict__ HW2, short* __restrict__ ws)
{
  __shared__ short t[64][65];
  const int bx   = (int)blockIdx.x;       // 0..31
  const int m    = bx >> 4;               // 0=V, 1=H
  const int tile = bx & 15;
  const int tr = tile >> 2, tc = tile & 3;
  const float* __restrict__ src = m ? HW2 : VW2;
  short* __restrict__ dN = ws + m * 131072;
  short* __restrict__ dT = dN + 65536;
  const int tid = (int)threadIdx.x;
  const int ri = tid >> 2;                // 0..63 local row
  const int cc = (tid & 3) * 16;          // local col chunk
  const int gr = tr*64 + ri;
#pragma unroll
  for (int j=0;j<16;j++){
    const int gc = tc*64 + cc + j;
    const short b = f2bf(src[gr*256 + gc]);
    dN[gr*256 + gc] = b;
    t[cc + j][ri] = b;
  }
  __syncthreads();
  const int cr = tid >> 2;                // local transposed row (= source col)
#pragma unroll
  for (int j=0;j<16;j++){
    const int sr = cc + j;                // source row local
    dT[(tc*64 + cr)*256 + tr*64 + sr] = t[cr][sr];
  }
}

extern "C" void kernel_launch(void* const* d_in, const int* in_sizes, int n_in,
                              void* d_out, int out_size, void* d_ws, size_t ws_size,
                              hipStream_t stream)
{
  const float* x   = (const float*)d_in[0];
  const float* VW1 = (const float*)d_in[1];
  const float* Vb1 = (const float*)d_in[2];
  const float* VW2 = (const float*)d_in[3];
  const float* Vb2 = (const float*)d_in[4];
  const float* HW1 = (const float*)d_in[5];
  const float* Hb1 = (const float*)d_in[6];
  const float* HW2 = (const float*)d_in[7];
  const float* Hb2 = (const float*)d_in[8];
  const float* HW3 = (const float*)d_in[9];
  const float* Hb3 = (const float*)d_in[10];
  const float* uW1 = (const float*)d_in[11];
  const float* ub1 = (const float*)d_in[12];
  const float* uW2 = (const float*)d_in[13];
  const float* ub2 = (const float*)d_in[14];

  short* wsbf = (short*)d_ws;             // needs 4*65536*2 = 512 KB of d_ws

  cvt_w<<<32, 256, 0, stream>>>(VW2, HW2, wsbf);
  fused<<<NB/MS, 256, 0, stream>>>(x, VW1, Vb1, Vb2, HW1, Hb1, Hb2, HW3, Hb3,
                                   uW1, ub1, uW2, ub2,
                                   wsbf, wsbf + 65536, wsbf + 131072, wsbf + 196608,
                                   (float*)d_out);
}